// Round 8
// baseline (289.080 us; speedup 1.0000x reference)
//
#include <hip/hip_runtime.h>
#include <hip/hip_bf16.h>
#include <math.h>

// Problem constants
#define NQ1 1001      // NQ+1 rows in embed tables
#define KK 5
#define MM 50
#define KD 64
#define VD 64
#define SD 50
#define BB 512
#define SS 500

#define NW 8          // waves per scan block
#define WIN 8         // scan steps per window
#define NWIN 62       // full windows (62*8 = 496; tail = 4 steps)

// Workspace layout (in floats)
#define OFF_ATTN   0                        // [1001][64] attn rows, cols 50..63 = 0
#define OFF_SQ     (OFF_ATTN + NQ1*64)      // [1001][64] q_embed @ Ws[64:128]
#define OFF_EAD    (OFF_SQ   + NQ1*64)      // [5005][128] interleaved (e,ad) per v
#define OFF_WST    (OFF_EAD  + NQ1*KK*128)  // [50][64] transposed top of Ws
#define OFF_WCT    (OFF_WST  + SD*64)       // [5][50] transposed Wc (pad to 256)
#define OFF_READS  (OFF_WCT  + 256)         // [512*500][64]

#define LGKM_BARRIER() asm volatile("s_waitcnt lgkmcnt(0)\n\ts_barrier" ::: "memory")

// ---------------- kernel 1: all tables (qtab softmax+Sq, transposes, ead) ----------------
__global__ __launch_bounds__(64) void k_tabs(
    const float* __restrict__ qtab, const float* __restrict__ itab,
    const float* __restrict__ keymem,
    const float* __restrict__ Wv, const float* __restrict__ bv,
    const float* __restrict__ We, const float* __restrict__ be,
    const float* __restrict__ Wa, const float* __restrict__ ba,
    const float* __restrict__ Ws, const float* __restrict__ Wc,
    float* __restrict__ attn_tab, float* __restrict__ sq_tab,
    float* __restrict__ ead_tab, float* __restrict__ WsT, float* __restrict__ WcT) {
  const int bid = blockIdx.x;
  const int t = threadIdx.x;

  if (bid < NQ1) {  // ---- per-question: attn softmax row + sq row ----
    const int q = bid;
    __shared__ float qe[64];
    qe[t] = qtab[q * KD + t];
    __syncthreads();

    float dot = 0.f;
    if (t < MM) {
#pragma unroll
      for (int i = 0; i < KD; ++i) dot = fmaf(qe[i], keymem[t * KD + i], dot);
    }
    float xv = (t < MM) ? dot : -1e30f;
#pragma unroll
    for (int off = 32; off; off >>= 1) xv = fmaxf(xv, __shfl_xor(xv, off));
    float p = (t < MM) ? __expf(dot - xv) : 0.f;
    float sum = p;
#pragma unroll
    for (int off = 32; off; off >>= 1) sum += __shfl_xor(sum, off);
    attn_tab[q * 64 + t] = p / sum;   // pad lanes (t>=50) write 0

    float sq = 0.f;
    if (t < SD) {
#pragma unroll
      for (int i = 0; i < KD; ++i) sq = fmaf(qe[i], Ws[(64 + i) * SD + t], sq);
    }
    sq_tab[q * 64 + t] = (t < SD) ? sq : 0.f;
    return;
  }

  if (bid == NQ1) {  // ---- transposes ----
    for (int idx = t; idx < 64 * SD; idx += 64) {
      int i = idx / SD, j = idx % SD;
      WsT[j * 64 + i] = Ws[idx];
    }
    for (int idx = t; idx < SD * KK; idx += 64) {
      int j = idx / KK, c = idx % KK;
      WcT[c * SD + j] = Wc[idx];
    }
    return;
  }

  // ---- per-(q,r) erase/add, interleaved ----
  const int qr = bid - (NQ1 + 1);
  const int q = qr / KK, r = qr % KK;
  const int v = t;
  __shared__ float item[64];
  __shared__ float ves[64];
  item[v] = itab[q * KD + v];
  __syncthreads();

  float ve = bv[v];
#pragma unroll
  for (int i = 0; i < KD; ++i) ve = fmaf(item[i], Wv[i * VD + v], ve);
#pragma unroll
  for (int k = 0; k < KK; ++k) {
    float rf = fmaxf(0.f, 1.f - fabsf((float)k - (float)r) * 0.25f);
    ve = fmaf(rf, Wv[(KD + k) * VD + v], ve);
  }
  ves[v] = ve;
  __syncthreads();

  float se = be[v], sa = ba[v];
#pragma unroll
  for (int i = 0; i < VD; ++i) {
    float x = ves[i];
    se = fmaf(x, We[i * VD + v], se);
    sa = fmaf(x, Wa[i * VD + v], sa);
  }
  float ex = __expf(2.f * sa);
  ead_tab[qr * 128 + 2 * v]     = 1.f / (1.f + __expf(-se));
  ead_tab[qr * 128 + 2 * v + 1] = (ex - 1.f) / (ex + 1.f);
}

// ---------------- kernel 2: scan — VMEM-fed register rings, LDS only for reduce ----------------
__global__ __launch_bounds__(512) void k_scan(
    const int* __restrict__ qs, const int* __restrict__ rs,
    const float* __restrict__ attn_tab, const float* __restrict__ ead_tab,
    const float* __restrict__ init_vm, float* __restrict__ reads) {
  const int b = blockIdx.x;
  const int tid = threadIdx.x;
  const int w = tid >> 6;       // wave id 0..7 (m-slots w*8 .. w*8+7)
  const int v = tid & 63;       // value column

  __shared__ float red[2][WIN][NW][64];   // 16 KB partial read sums
  __shared__ int2  sidx[512];             // 4 KB per-step (attn byte-off, ead byte-off)

  const int* __restrict__ qb = qs + b * SS;
  const int* __restrict__ rb = rs + b * SS;
  float* __restrict__ outp = reads + (size_t)b * SS * 64;

  // ---- stage per-step byte offsets once (entries 500..511 clamped) ----
  {
    int idx = (tid < SS) ? tid : (SS - 1);
    int q = qb[idx], r = rb[idx];
    sidx[tid] = make_int2(q * 256, (q * KK + r) * 512);
  }

  float vm[8];
#pragma unroll
  for (int i = 0; i < 8; ++i) {
    int m = w * 8 + i;
    vm[i] = (m < MM) ? init_vm[m * VD + v] : 0.f;
  }
  __syncthreads();

  const char* __restrict__ atb = (const char*)attn_tab;
  const char* __restrict__ edb = (const char*)ead_tab;
  const int mbB = w * 32;      // byte offset of this wave's 8-float m-slice
  const int vB8 = v * 8;       // byte offset of this lane's (e,ad) pair

  // 4-deep register rings: data for steps s..s+3, offsets for steps s+4..s+7
  float4 da[4][2];
  float2 de[4];
  int2   ofr[4];

#pragma unroll
  for (int k = 0; k < 4; ++k) {
    int2 o = sidx[k];
    const char* pa = atb + (o.x + mbB);
    da[k][0] = *(const float4*)(pa);
    da[k][1] = *(const float4*)(pa + 16);
    de[k] = *(const float2*)(edb + (o.y + vB8));
  }
#pragma unroll
  for (int k = 0; k < 4; ++k) {
    int2 o = sidx[k + 4];
    ofr[k] = make_int2(o.x + mbB, o.y + vB8);
  }

#define STEP(buf_, wi_, kk) {                                         \
    float4 a0 = da[(kk) & 3][0];                                      \
    float4 a1 = da[(kk) & 3][1];                                      \
    float ee = de[(kk) & 3].x, aa = de[(kk) & 3].y;                   \
    float acc0, acc1;                                                 \
    acc0 = a0.x * vm[0];                                              \
    vm[0] = fmaf(a0.x, fmaf(-ee, vm[0], aa), vm[0]);                  \
    acc1 = a0.y * vm[1];                                              \
    vm[1] = fmaf(a0.y, fmaf(-ee, vm[1], aa), vm[1]);                  \
    acc0 = fmaf(a0.z, vm[2], acc0);                                   \
    vm[2] = fmaf(a0.z, fmaf(-ee, vm[2], aa), vm[2]);                  \
    acc1 = fmaf(a0.w, vm[3], acc1);                                   \
    vm[3] = fmaf(a0.w, fmaf(-ee, vm[3], aa), vm[3]);                  \
    acc0 = fmaf(a1.x, vm[4], acc0);                                   \
    vm[4] = fmaf(a1.x, fmaf(-ee, vm[4], aa), vm[4]);                  \
    acc1 = fmaf(a1.y, vm[5], acc1);                                   \
    vm[5] = fmaf(a1.y, fmaf(-ee, vm[5], aa), vm[5]);                  \
    acc0 = fmaf(a1.z, vm[6], acc0);                                   \
    vm[6] = fmaf(a1.z, fmaf(-ee, vm[6], aa), vm[6]);                  \
    acc1 = fmaf(a1.w, vm[7], acc1);                                   \
    vm[7] = fmaf(a1.w, fmaf(-ee, vm[7], aa), vm[7]);                  \
    red[buf_][kk][w][v] = acc0 + acc1;                                \
    /* refill data slot for step s+4 (offsets ready in ofr) */        \
    { int2 o = ofr[(kk) & 3];                                         \
      const char* pa = atb + o.x;                                     \
      da[(kk) & 3][0] = *(const float4*)(pa);                         \
      da[(kk) & 3][1] = *(const float4*)(pa + 16);                    \
      de[(kk) & 3] = *(const float2*)(edb + o.y); }                   \
    /* offset refill for step s+8 from LDS (clamped past end) */      \
    { int2 nn = sidx[(wi_) * WIN + (kk) + 8];                         \
      ofr[(kk) & 3] = make_int2(nn.x + mbB, nn.y + vB8); }            \
  }

#define FLUSH(fw_) {                                                  \
    const int pb = (fw_) & 1;                                         \
    float s = 0.f;                                                    \
    _Pragma("unroll")                                                 \
    for (int wv = 0; wv < NW; ++wv) s += red[pb][w][wv][v];           \
    outp[(size_t)(fw_) * 512 + tid] = s;                              \
  }

  for (int wi = 0; wi < NWIN; ++wi) {
    const int buf = wi & 1;
    // flush previous window (reads other red buffer; store fire-and-forget)
    if (wi > 0) FLUSH(wi - 1);
    STEP(buf, wi, 0); STEP(buf, wi, 1); STEP(buf, wi, 2); STEP(buf, wi, 3);
    STEP(buf, wi, 4); STEP(buf, wi, 5); STEP(buf, wi, 6); STEP(buf, wi, 7);
    // window barrier: drains LDS ops only; VMEM loads/stores stay in flight
    LGKM_BARRIER();
  }

  // ---- tail: window 62 = steps 496..499 (buf 0) ----
  FLUSH(NWIN - 1);
  STEP(0, NWIN, 0); STEP(0, NWIN, 1); STEP(0, NWIN, 2); STEP(0, NWIN, 3);
  LGKM_BARRIER();
  if (w < (SS - NWIN * WIN)) {
    float s = 0.f;
#pragma unroll
    for (int wv = 0; wv < NW; ++wv) s += red[0][w][wv][v];
    outp[(size_t)NWIN * 512 + tid] = s;
  }
#undef STEP
#undef FLUSH
}

// ---------------- kernel 3: summary + logits + softmax ----------------
__global__ __launch_bounds__(64) void k_out(
    const float* __restrict__ reads, const int* __restrict__ qs,
    const float* __restrict__ sq_tab, const float* __restrict__ WsT,
    const float* __restrict__ bs, const float* __restrict__ WcT,
    const float* __restrict__ bc,
    float* __restrict__ out_logits, float* __restrict__ out_probs) {
  __shared__ float xs[64 * 65];
  const int lane = threadIdx.x;
  const long rowbase = (long)blockIdx.x * 64;
  const float* __restrict__ src = reads + rowbase * 64;

#pragma unroll 8
  for (int it = 0; it < 64; ++it)
    xs[it * 65 + lane] = src[it * 64 + lane];
  __syncthreads();

  float x[64];
#pragma unroll
  for (int i = 0; i < 64; ++i) x[i] = xs[lane * 65 + i];

  const long row = rowbase + lane;
  const int q = qs[row];
  const float* __restrict__ sqrow = sq_tab + (long)q * 64;

  float sm[SD];
#pragma unroll
  for (int j = 0; j < SD; ++j) {
    float acc = bs[j] + sqrow[j];
    const float* __restrict__ wrow = WsT + j * 64;  // uniform -> s_load
#pragma unroll
    for (int i = 0; i < 64; ++i) acc = fmaf(x[i], wrow[i], acc);
    float ex = __expf(2.f * acc);
    sm[j] = (ex - 1.f) / (ex + 1.f);
  }

  float lg[KK];
#pragma unroll
  for (int c = 0; c < KK; ++c) {
    float acc = bc[c];
    const float* __restrict__ wrow = WcT + c * SD;  // uniform -> s_load
#pragma unroll
    for (int j = 0; j < SD; ++j) acc = fmaf(sm[j], wrow[j], acc);
    lg[c] = acc;
  }

  float mx = lg[0];
#pragma unroll
  for (int c = 1; c < KK; ++c) mx = fmaxf(mx, lg[c]);
  float p[KK], sum = 0.f;
#pragma unroll
  for (int c = 0; c < KK; ++c) { p[c] = __expf(lg[c] - mx); sum += p[c]; }
  float inv = 1.f / sum;
#pragma unroll
  for (int c = 0; c < KK; ++c) {
    out_logits[row * KK + c] = lg[c];
    out_probs[row * KK + c] = p[c] * inv;
  }
}

extern "C" void kernel_launch(void* const* d_in, const int* in_sizes, int n_in,
                              void* d_out, int out_size, void* d_ws, size_t ws_size,
                              hipStream_t stream) {
  const int*   questions  = (const int*)  d_in[0];
  const int*   responses  = (const int*)  d_in[1];
  const float* q_table    = (const float*)d_in[2];
  const float* item_table = (const float*)d_in[3];
  const float* Wv         = (const float*)d_in[4];
  const float* bv         = (const float*)d_in[5];
  const float* key_mem    = (const float*)d_in[6];
  const float* init_vm    = (const float*)d_in[7];
  const float* We         = (const float*)d_in[8];
  const float* be         = (const float*)d_in[9];
  const float* Wa         = (const float*)d_in[10];
  const float* ba         = (const float*)d_in[11];
  const float* Ws         = (const float*)d_in[12];
  const float* bs         = (const float*)d_in[13];
  const float* Wc         = (const float*)d_in[14];
  const float* bc         = (const float*)d_in[15];

  float* ws       = (float*)d_ws;
  float* attn_tab = ws + OFF_ATTN;
  float* sq_tab   = ws + OFF_SQ;
  float* ead_tab  = ws + OFF_EAD;
  float* WsT      = ws + OFF_WST;
  float* WcT      = ws + OFF_WCT;
  float* reads    = ws + OFF_READS;

  float* out_logits = (float*)d_out;
  float* out_probs  = out_logits + (size_t)BB * SS * KK;

  hipLaunchKernelGGL(k_tabs, dim3(NQ1 + 1 + NQ1 * KK), dim3(64), 0, stream,
                     q_table, item_table, key_mem, Wv, bv, We, be, Wa, ba, Ws, Wc,
                     attn_tab, sq_tab, ead_tab, WsT, WcT);
  hipLaunchKernelGGL(k_scan, dim3(BB), dim3(NW * 64), 0, stream,
                     questions, responses, attn_tab, ead_tab, init_vm, reads);
  hipLaunchKernelGGL(k_out, dim3(BB * SS / 64), dim3(64), 0, stream,
                     reads, questions, sq_tab, WsT, bs, WcT, bc,
                     out_logits, out_probs);
}

// Round 9
// 225.390 us; speedup vs baseline: 1.2826x; 1.2826x over previous
//
#include <hip/hip_runtime.h>
#include <hip/hip_bf16.h>
#include <math.h>

typedef float v2f __attribute__((ext_vector_type(2)));
typedef float v4f __attribute__((ext_vector_type(4)));

// Problem constants
#define NQ1 1001      // NQ+1 rows in embed tables
#define KK 5
#define MM 50
#define KD 64
#define VD 64
#define SD 50
#define BB 512
#define SS 500

#define NW 8          // waves per scan block
#define WIN 8         // scan steps per window
#define NWIN 62       // full windows (62*8 = 496; tail = 4 steps = 2 pairs)

// Workspace layout (in floats)
#define OFF_ATTN   0                        // [1001][64] attn rows, cols 50..63 = 0
#define OFF_SQ     (OFF_ATTN + NQ1*64)      // [1001][64] q_embed @ Ws[64:128]
#define OFF_EAD    (OFF_SQ   + NQ1*64)      // [5005][128] interleaved (e,ad) per v
#define OFF_WST    (OFF_EAD  + NQ1*KK*128)  // [50][64] transposed top of Ws
#define OFF_WCT    (OFF_WST  + SD*64)       // [5][50] transposed Wc (pad to 256)
#define OFF_READS  (OFF_WCT  + 256)         // [512*500][64]

#define LGKM_BARRIER() asm volatile("s_waitcnt lgkmcnt(0)\n\ts_barrier" ::: "memory")

// ---------------- kernel 1: all tables (qtab softmax+Sq, transposes, ead) ----------------
__global__ __launch_bounds__(64) void k_tabs(
    const float* __restrict__ qtab, const float* __restrict__ itab,
    const float* __restrict__ keymem,
    const float* __restrict__ Wv, const float* __restrict__ bv,
    const float* __restrict__ We, const float* __restrict__ be,
    const float* __restrict__ Wa, const float* __restrict__ ba,
    const float* __restrict__ Ws, const float* __restrict__ Wc,
    float* __restrict__ attn_tab, float* __restrict__ sq_tab,
    float* __restrict__ ead_tab, float* __restrict__ WsT, float* __restrict__ WcT) {
  const int bid = blockIdx.x;
  const int t = threadIdx.x;

  if (bid < NQ1) {  // ---- per-question: attn softmax row + sq row ----
    const int q = bid;
    __shared__ float qe[64];
    qe[t] = qtab[q * KD + t];
    __syncthreads();

    float dot = 0.f;
    if (t < MM) {
#pragma unroll
      for (int i = 0; i < KD; ++i) dot = fmaf(qe[i], keymem[t * KD + i], dot);
    }
    float xv = (t < MM) ? dot : -1e30f;
#pragma unroll
    for (int off = 32; off; off >>= 1) xv = fmaxf(xv, __shfl_xor(xv, off));
    float p = (t < MM) ? __expf(dot - xv) : 0.f;
    float sum = p;
#pragma unroll
    for (int off = 32; off; off >>= 1) sum += __shfl_xor(sum, off);
    attn_tab[q * 64 + t] = p / sum;   // pad lanes (t>=50) write 0

    float sq = 0.f;
    if (t < SD) {
#pragma unroll
      for (int i = 0; i < KD; ++i) sq = fmaf(qe[i], Ws[(64 + i) * SD + t], sq);
    }
    sq_tab[q * 64 + t] = (t < SD) ? sq : 0.f;
    return;
  }

  if (bid == NQ1) {  // ---- transposes ----
    for (int idx = t; idx < 64 * SD; idx += 64) {
      int i = idx / SD, j = idx % SD;
      WsT[j * 64 + i] = Ws[idx];
    }
    for (int idx = t; idx < SD * KK; idx += 64) {
      int j = idx / KK, c = idx % KK;
      WcT[c * SD + j] = Wc[idx];
    }
    return;
  }

  // ---- per-(q,r) erase/add, interleaved ----
  const int qr = bid - (NQ1 + 1);
  const int q = qr / KK, r = qr % KK;
  const int v = t;
  __shared__ float item[64];
  __shared__ float ves[64];
  item[v] = itab[q * KD + v];
  __syncthreads();

  float ve = bv[v];
#pragma unroll
  for (int i = 0; i < KD; ++i) ve = fmaf(item[i], Wv[i * VD + v], ve);
#pragma unroll
  for (int k = 0; k < KK; ++k) {
    float rf = fmaxf(0.f, 1.f - fabsf((float)k - (float)r) * 0.25f);
    ve = fmaf(rf, Wv[(KD + k) * VD + v], ve);
  }
  ves[v] = ve;
  __syncthreads();

  float se = be[v], sa = ba[v];
#pragma unroll
  for (int i = 0; i < VD; ++i) {
    float x = ves[i];
    se = fmaf(x, We[i * VD + v], se);
    sa = fmaf(x, Wa[i * VD + v], sa);
  }
  float ex = __expf(2.f * sa);
  ead_tab[qr * 128 + 2 * v]     = 1.f / (1.f + __expf(-se));
  ead_tab[qr * 128 + 2 * v + 1] = (ex - 1.f) / (ex + 1.f);
}

// ---------------- kernel 2: scan — VMEM a-ring (8 deep) + paired-ead LDS + pk-f32 ----------------
__global__ __launch_bounds__(512, 4) void k_scan(
    const int* __restrict__ qs, const int* __restrict__ rs,
    const float* __restrict__ attn_tab, const float* __restrict__ ead_tab,
    const float* __restrict__ init_vm, float* __restrict__ reads) {
  const int b = blockIdx.x;
  const int tid = threadIdx.x;
  const int w = tid >> 6;       // wave id 0..7 (m-slots w*8 .. w*8+7)
  const int v = tid & 63;       // value column
  const uint32_t mbB = w * 32;  // byte offset of wave's 8-float m-slice
  const uint32_t v8 = v * 8;    // byte offset of lane's (e,ad) pair

  __shared__ v2f red2[2][4][NW][64];           // 32 KB paired read partials
  __shared__ v4f eadbuf[2][4][64];             // 8 KB (e0,ad0,e1,ad1) per pair
  __shared__ __align__(16) int sidx_a[512];    // 2 KB per-step attn byte offset
  __shared__ __align__(16) int sidx_e[512];    // 2 KB per-step ead byte offset

  const int* __restrict__ qb = qs + b * SS;
  const int* __restrict__ rb = rs + b * SS;
  float* __restrict__ outp = reads + (size_t)b * SS * 64;
  const char* __restrict__ atb = (const char*)attn_tab;
  const char* __restrict__ edb = (const char*)ead_tab;

  // ---- prologue: fill offset tables (clamped past 499) ----
  {
    int idx = (tid < SS) ? tid : (SS - 1);
    int q = qb[idx], r = rb[idx];
    sidx_a[tid] = q << 8;
    sidx_e[tid] = (q * KK + r) << 9;
  }

  v2f vm0, vm1, vm2, vm3;
  {
    int m = w * 8;
    vm0.x = init_vm[(m + 0) * VD + v]; vm0.y = init_vm[(m + 1) * VD + v];
    vm1.x = init_vm[(m + 2) * VD + v]; vm1.y = init_vm[(m + 3) * VD + v];
    if (m + 4 < MM) {
      vm2.x = init_vm[(m + 4) * VD + v]; vm2.y = init_vm[(m + 5) * VD + v];
    } else { vm2 = (v2f)(0.f); }
    if (m + 6 < MM) {
      vm3.x = init_vm[(m + 6) * VD + v]; vm3.y = init_vm[(m + 7) * VD + v];
    } else { vm3 = (v2f)(0.f); }
    if (m + 4 < MM && m + 6 >= MM) { vm3 = (v2f)(0.f); }
  }
  __syncthreads();

  // ---- stage window 0 ead (waves 0-3) + init a-ring slots 0..7 (all waves) ----
  if (w < 4) {
    int2 eo = *(const int2*)&sidx_e[2 * w];
    v2f g0 = *(const v2f*)(edb + (uint32_t)eo.x + v8);
    v2f g1 = *(const v2f*)(edb + (uint32_t)eo.y + v8);
    eadbuf[0][w][v] = (v4f){g0.x, g0.y, g1.x, g1.y};
  }

  v4f da[8][2];
  {
    int4 oL = *(const int4*)&sidx_a[0];
    int4 oH = *(const int4*)&sidx_a[4];
#define INITSLOT(s_, o_) { uint32_t o = (uint32_t)(o_) + mbB;          \
      da[s_][0] = *(const v4f*)(atb + o);                              \
      da[s_][1] = *(const v4f*)(atb + o + 16); }
    INITSLOT(0, oL.x) INITSLOT(1, oL.y) INITSLOT(2, oL.z) INITSLOT(3, oL.w)
    INITSLOT(4, oH.x) INITSLOT(5, oH.y) INITSLOT(6, oH.z) INITSLOT(7, oH.w)
#undef INITSLOT
  }
  __syncthreads();

  // One PAIR = steps 2p, 2p+1 of the window. a-slot = 2p/2p+1 (static).
  // Uses old vm for acc, then updates vm (matches reference order).
#define HALF(aL_, aH_, e2_, ad2_, accname_) float accname_;            \
  { v2f acc = aL_.lo * vmw0;                                           \
    vmw0 += aL_.lo * (ad2_ - e2_ * vmw0);                              \
    acc += aL_.hi * vmw1;                                              \
    vmw1 += aL_.hi * (ad2_ - e2_ * vmw1);                              \
    acc += aH_.lo * vmw2;                                              \
    vmw2 += aH_.lo * (ad2_ - e2_ * vmw2);                              \
    acc += aH_.hi * vmw3;                                              \
    vmw3 += aH_.hi * (ad2_ - e2_ * vmw3);                              \
    accname_ = acc.x + acc.y; }

#define PAIR(buf_, p_, oA_, oB_) {                                     \
    v4f ed = edreg[(p_) & 1];                                          \
    if ((p_) < 3) edreg[((p_) + 1) & 1] = eadbuf[buf_][(p_) + 1][v];   \
    v2f e2A = {ed.x, ed.x}, ad2A = {ed.y, ed.y};                       \
    v2f e2B = {ed.z, ed.z}, ad2B = {ed.w, ed.w};                       \
    v4f aL0 = da[2 * (p_)][0],     aH0 = da[2 * (p_)][1];              \
    v4f aL1 = da[2 * (p_) + 1][0], aH1 = da[2 * (p_) + 1][1];          \
    HALF(aL0, aH0, e2A, ad2A, accA)                                    \
    { uint32_t o = (uint32_t)(oA_) + mbB;                              \
      da[2 * (p_)][0] = *(const v4f*)(atb + o);                        \
      da[2 * (p_)][1] = *(const v4f*)(atb + o + 16); }                 \
    HALF(aL1, aH1, e2B, ad2B, accB)                                    \
    { uint32_t o = (uint32_t)(oB_) + mbB;                              \
      da[2 * (p_) + 1][0] = *(const v4f*)(atb + o);                    \
      da[2 * (p_) + 1][1] = *(const v4f*)(atb + o + 16); }             \
    red2[buf_][p_][w][v] = (v2f){accA, accB};                          \
  }

  for (int wi = 0; wi < NWIN; ++wi) {
    const int buf = wi & 1;
    const int nb = buf ^ 1;
    // rename vm for macro use
    v2f& vmw0 = vm0; v2f& vmw1 = vm1; v2f& vmw2 = vm2; v2f& vmw3 = vm3;

    // a-offsets for this window's refills (steps wi*8+8 .. +15; clamped entries ok)
    int4 aoffL = *(const int4*)&sidx_a[wi * 8 + 8];
    int4 aoffH = *(const int4*)&sidx_a[wi * 8 + 12];

    // staging issue (waves 0-3): gather window wi+1's ead pairs
    v2f g0, g1;
    if (w < 4) {
      int2 eo = *(const int2*)&sidx_e[(wi + 1) * 8 + 2 * w];
      g0 = *(const v2f*)(edb + (uint32_t)eo.x + v8);
      g1 = *(const v2f*)(edb + (uint32_t)eo.y + v8);
    }

    // flush window wi-1 (waves 4-7): red2[nb] -> global
    if (w >= 4 && wi > 0) {
      const int pf = w - 4;
      v2f s = (v2f)(0.f);
#pragma unroll
      for (int wv = 0; wv < NW; ++wv) s += red2[nb][pf][wv][v];
      size_t rowb = (size_t)((wi - 1) * WIN + 2 * pf) * 64 + v;
      outp[rowb] = s.x;
      outp[rowb + 64] = s.y;
    }

    // compute 4 pairs (8 steps)
    v4f edreg[2];
    edreg[0] = eadbuf[buf][0][v];
    PAIR(buf, 0, aoffL.x, aoffL.y)
    PAIR(buf, 1, aoffL.z, aoffL.w)
    PAIR(buf, 2, aoffH.x, aoffH.y)
    PAIR(buf, 3, aoffH.z, aoffH.w)

    // staging write (waves 0-3)
    if (w < 4) eadbuf[nb][w][v] = (v4f){g0.x, g0.y, g1.x, g1.y};

    LGKM_BARRIER();
  }

  // ---- tail window (wi = 62, buf 0): 2 pairs = steps 496..499 ----
  {
    v2f& vmw0 = vm0; v2f& vmw1 = vm1; v2f& vmw2 = vm2; v2f& vmw3 = vm3;
    int4 aoffL = *(const int4*)&sidx_a[NWIN * 8 + 8];   // clamped, harmless
    // flush window 61 (red2[1])
    if (w >= 4) {
      const int pf = w - 4;
      v2f s = (v2f)(0.f);
#pragma unroll
      for (int wv = 0; wv < NW; ++wv) s += red2[1][pf][wv][v];
      size_t rowb = (size_t)((NWIN - 1) * WIN + 2 * pf) * 64 + v;
      outp[rowb] = s.x;
      outp[rowb + 64] = s.y;
    }
    v4f edreg[2];
    edreg[0] = eadbuf[0][0][v];
    PAIR(0, 0, aoffL.x, aoffL.y)
    PAIR(0, 1, aoffL.z, aoffL.w)
    LGKM_BARRIER();
    // final flush: window 62 pairs 0,1 (rows 496..499)
    if (w >= 4 && w < 6) {
      const int pf = w - 4;
      v2f s = (v2f)(0.f);
#pragma unroll
      for (int wv = 0; wv < NW; ++wv) s += red2[0][pf][wv][v];
      size_t rowb = (size_t)(NWIN * WIN + 2 * pf) * 64 + v;
      outp[rowb] = s.x;
      outp[rowb + 64] = s.y;
    }
  }
#undef PAIR
#undef HALF
}

// ---------------- kernel 3: summary + logits + softmax ----------------
__global__ __launch_bounds__(64) void k_out(
    const float* __restrict__ reads, const int* __restrict__ qs,
    const float* __restrict__ sq_tab, const float* __restrict__ WsT,
    const float* __restrict__ bs, const float* __restrict__ WcT,
    const float* __restrict__ bc,
    float* __restrict__ out_logits, float* __restrict__ out_probs) {
  __shared__ float xs[64 * 65];
  const int lane = threadIdx.x;
  const long rowbase = (long)blockIdx.x * 64;
  const float* __restrict__ src = reads + rowbase * 64;

#pragma unroll 8
  for (int it = 0; it < 64; ++it)
    xs[it * 65 + lane] = src[it * 64 + lane];
  __syncthreads();

  float x[64];
#pragma unroll
  for (int i = 0; i < 64; ++i) x[i] = xs[lane * 65 + i];

  const long row = rowbase + lane;
  const int q = qs[row];
  const float* __restrict__ sqrow = sq_tab + (long)q * 64;

  float sm[SD];
#pragma unroll
  for (int j = 0; j < SD; ++j) {
    float acc = bs[j] + sqrow[j];
    const float* __restrict__ wrow = WsT + j * 64;  // uniform -> s_load
#pragma unroll
    for (int i = 0; i < 64; ++i) acc = fmaf(x[i], wrow[i], acc);
    float ex = __expf(2.f * acc);
    sm[j] = (ex - 1.f) / (ex + 1.f);
  }

  float lg[KK];
#pragma unroll
  for (int c = 0; c < KK; ++c) {
    float acc = bc[c];
    const float* __restrict__ wrow = WcT + c * SD;  // uniform -> s_load
#pragma unroll
    for (int j = 0; j < SD; ++j) acc = fmaf(sm[j], wrow[j], acc);
    lg[c] = acc;
  }

  float mx = lg[0];
#pragma unroll
  for (int c = 1; c < KK; ++c) mx = fmaxf(mx, lg[c]);
  float p[KK], sum = 0.f;
#pragma unroll
  for (int c = 0; c < KK; ++c) { p[c] = __expf(lg[c] - mx); sum += p[c]; }
  float inv = 1.f / sum;
#pragma unroll
  for (int c = 0; c < KK; ++c) {
    out_logits[row * KK + c] = lg[c];
    out_probs[row * KK + c] = p[c] * inv;
  }
}

extern "C" void kernel_launch(void* const* d_in, const int* in_sizes, int n_in,
                              void* d_out, int out_size, void* d_ws, size_t ws_size,
                              hipStream_t stream) {
  const int*   questions  = (const int*)  d_in[0];
  const int*   responses  = (const int*)  d_in[1];
  const float* q_table    = (const float*)d_in[2];
  const float* item_table = (const float*)d_in[3];
  const float* Wv         = (const float*)d_in[4];
  const float* bv         = (const float*)d_in[5];
  const float* key_mem    = (const float*)d_in[6];
  const float* init_vm    = (const float*)d_in[7];
  const float* We         = (const float*)d_in[8];
  const float* be         = (const float*)d_in[9];
  const float* Wa         = (const float*)d_in[10];
  const float* ba         = (const float*)d_in[11];
  const float* Ws         = (const float*)d_in[12];
  const float* bs         = (const float*)d_in[13];
  const float* Wc         = (const float*)d_in[14];
  const float* bc         = (const float*)d_in[15];

  float* ws       = (float*)d_ws;
  float* attn_tab = ws + OFF_ATTN;
  float* sq_tab   = ws + OFF_SQ;
  float* ead_tab  = ws + OFF_EAD;
  float* WsT      = ws + OFF_WST;
  float* WcT      = ws + OFF_WCT;
  float* reads    = ws + OFF_READS;

  float* out_logits = (float*)d_out;
  float* out_probs  = out_logits + (size_t)BB * SS * KK;

  hipLaunchKernelGGL(k_tabs, dim3(NQ1 + 1 + NQ1 * KK), dim3(64), 0, stream,
                     q_table, item_table, key_mem, Wv, bv, We, be, Wa, ba, Ws, Wc,
                     attn_tab, sq_tab, ead_tab, WsT, WcT);
  hipLaunchKernelGGL(k_scan, dim3(BB), dim3(NW * 64), 0, stream,
                     questions, responses, attn_tab, ead_tab, init_vm, reads);
  hipLaunchKernelGGL(k_out, dim3(BB * SS / 64), dim3(64), 0, stream,
                     reads, questions, sq_tab, WsT, bs, WcT, bc,
                     out_logits, out_probs);
}